// Round 2
// baseline (520.012 us; speedup 1.0000x reference)
//
#include <hip/hip_runtime.h>
#include <hip/hip_bf16.h>
#include <math.h>

#define F4(p)  (*(float4*)(p))
#define CF4(p) (*(const float4*)(p))

namespace {
constexpr int BB   = 32;    // batch
constexpr int LL   = 4096;  // sequence
constexpr int HH   = 64;    // channels
constexpr int MMo  = 64;    // retained modes
constexpr int ROWS = BB * HH;      // 2048
constexpr int K2   = 2 * MMo;      // 128 (re/im interleaved)

__device__ __forceinline__ float gelu_tanh(float x) {
    // jax.nn.gelu approximate=True
    float inner = 0.7978845608028654f * (x + 0.044715f * x * x * x);
    return 0.5f * x * (1.0f + tanhf(inner));
}
} // namespace

// ---------------------------------------------------------------------------
// Twiddle tables:
//   Tdft[l*128 + 2m]   =  cos(2*pi*m*l/L)      (DFT real part weight)
//   Tdft[l*128 + 2m+1] = -sin(2*pi*m*l/L)      (DFT imag part weight)
//   Trec[(2m)*L + l]   = (m==0 ? 1 : 2*cos)/L  (irfft weight on Re)
//   Trec[(2m+1)*L + l] = (m==0 ? 0 : -2*sin)/L (irfft weight on Im; Im(a0) dropped)
// ---------------------------------------------------------------------------
__global__ __launch_bounds__(256) void k_twiddle(float* __restrict__ Tdft,
                                                 float* __restrict__ Trec) {
    int idx = blockIdx.x * 256 + threadIdx.x;   // 0 .. 262143
    int l = idx >> 6, m = idx & 63;
    float ang = (float)((l * m) & 4095) * (6.283185307179586f / 4096.0f);
    float s, c;
    sincosf(ang, &s, &c);
    Tdft[l * 128 + 2 * m]     = c;
    Tdft[l * 128 + 2 * m + 1] = -s;
    const float sc = 1.0f / 4096.0f;
    Trec[(size_t)(2 * m) * LL + l]     = (m == 0) ? sc : 2.0f * sc * c;
    Trec[(size_t)(2 * m + 1) * LL + l] = (m == 0) ? 0.0f : -2.0f * sc * s;
}

// ---------------------------------------------------------------------------
// Lift: x0[b][h][l] = b_lift[h] + sum_c w_lift[h][c] * concat(u[b,l,:],z[b,:])[c]
// ---------------------------------------------------------------------------
__global__ __launch_bounds__(256) void k_lift(const float* __restrict__ u,
                                              const float* __restrict__ z,
                                              const float* __restrict__ wl,
                                              const float* __restrict__ bl,
                                              float* __restrict__ x0) {
    __shared__ float wsh[64 * 16];
    __shared__ float bsh[64];
    const int t = threadIdx.x;
    for (int i = t; i < 1024; i += 256) wsh[i] = wl[i];
    if (t < 64) bsh[t] = bl[t];
    __syncthreads();
    const int b = blockIdx.y;
    const int l = blockIdx.x * 256 + t;
    float in[16];
    const float* up = u + ((size_t)b * LL + l) * 8;
#pragma unroll
    for (int c = 0; c < 8; ++c) in[c] = up[c];
#pragma unroll
    for (int c = 0; c < 8; ++c) in[8 + c] = z[b * 8 + c];
    float* xp = x0 + (size_t)b * HH * LL + l;
    for (int h = 0; h < 64; ++h) {
        float acc = bsh[h];
#pragma unroll
        for (int c = 0; c < 16; ++c) acc += wsh[h * 16 + c] * in[c];
        xp[(size_t)h * LL] = acc;
    }
}

// ---------------------------------------------------------------------------
// Partial DFT (split-K GEMM): Y[ch][row][m2] = sum_{l in chunk} x[row][l]*Tdft[l][m2]
// grid (32 row-tiles, 8 K-chunks), block 256. Tile 64 rows x 128 cols.
// ---------------------------------------------------------------------------
__global__ __launch_bounds__(256) void k_dft(const float* __restrict__ x,
                                             const float* __restrict__ Tdft,
                                             float* __restrict__ Y) {
    __shared__ float Asl[64 * 36];    // 64 rows x 32 k, stride 36 (bank pad)
    __shared__ float Bsl[32 * 128];   // 32 k x 128 cols
    const int t = threadIdx.x;
    const int row0 = blockIdx.x * 64;
    const int ch = blockIdx.y;
    const int lsub = t & 15, osub = t >> 4;
    float acc[4][8];
#pragma unroll
    for (int j = 0; j < 4; ++j)
#pragma unroll
        for (int jj = 0; jj < 8; ++jj) acc[j][jj] = 0.0f;

    const int ar = t >> 2, aq = t & 3;
    for (int kc = 0; kc < 512; kc += 32) {
        const int l0 = ch * 512 + kc;
        __syncthreads();
        {   // stage A tile: 64 rows x 32 l
            const float* src = x + (size_t)(row0 + ar) * LL + l0 + aq * 8;
            float4 v0 = CF4(src);
            float4 v1 = CF4(src + 4);
            F4(&Asl[ar * 36 + aq * 8]) = v0;
            F4(&Asl[ar * 36 + aq * 8 + 4]) = v1;
        }
        {   // stage B tile: contiguous 32x128 block of Tdft
            const float4* src = (const float4*)(Tdft + (size_t)l0 * 128);
            float4* dst = (float4*)Bsl;
#pragma unroll
            for (int i = 0; i < 4; ++i) dst[t + i * 256] = src[t + i * 256];
        }
        __syncthreads();
#pragma unroll 2
        for (int k4 = 0; k4 < 32; k4 += 4) {
            float va[4][4];
#pragma unroll
            for (int j = 0; j < 4; ++j) {
                float4 a = CF4(&Asl[(osub * 4 + j) * 36 + k4]);
                va[j][0] = a.x; va[j][1] = a.y; va[j][2] = a.z; va[j][3] = a.w;
            }
#pragma unroll
            for (int dk = 0; dk < 4; ++dk) {
#pragma unroll
                for (int jj = 0; jj < 8; ++jj) {
                    float bv = Bsl[(k4 + dk) * 128 + lsub + 16 * jj];
                    acc[0][jj] += va[0][dk] * bv;
                    acc[1][jj] += va[1][dk] * bv;
                    acc[2][jj] += va[2][dk] * bv;
                    acc[3][jj] += va[3][dk] * bv;
                }
            }
        }
    }
    float* yp = Y + ((size_t)ch * ROWS + row0) * 128;
#pragma unroll
    for (int j = 0; j < 4; ++j)
#pragma unroll
        for (int jj = 0; jj < 8; ++jj)
            yp[(osub * 4 + j) * 128 + lsub + 16 * jj] = acc[j][jj];
}

// Reduce split-K partials: Xf = sum_ch Y[ch]
__global__ __launch_bounds__(256) void k_redY(const float* __restrict__ Y,
                                              float* __restrict__ Xf) {
    int idx = blockIdx.x * 256 + threadIdx.x;   // < 262144
    float s = 0.0f;
#pragma unroll
    for (int c = 0; c < 8; ++c) s += Y[(size_t)c * 262144 + idx];
    Xf[idx] = s;
}

// ---------------------------------------------------------------------------
// Spectral mix: Of[b][o][m] = sum_i Xf[b][i][m] * (wr[o][i][m] + j*wi[o][i][m])
// grid (16 o-groups, 32 b), block 256 = 64 lanes(m) x 4 (o within group).
// ---------------------------------------------------------------------------
__global__ __launch_bounds__(256) void k_spec(const float* __restrict__ Xf,
                                              const float* __restrict__ wr,
                                              const float* __restrict__ wi,
                                              float* __restrict__ Of, int layer) {
    __shared__ float xsh[64 * 128];
    const int t = threadIdx.x;
    const int b = blockIdx.y;
    const int og = blockIdx.x;
    {   // stage Xf[b] (contiguous 8192 floats)
        const float4* src = (const float4*)(Xf + (size_t)b * HH * 128);
        float4* dst = (float4*)xsh;
#pragma unroll
        for (int i = 0; i < 8; ++i) dst[t + i * 256] = src[t + i * 256];
    }
    __syncthreads();
    const int m = t & 63, osub = t >> 6;
    const int o = og * 4 + osub;
    const float* wrp = wr + ((size_t)layer * HH + o) * HH * MMo + m;
    const float* wip = wi + ((size_t)layer * HH + o) * HH * MMo + m;
    float are = 0.0f, aim = 0.0f;
    const float2* xs2 = (const float2*)xsh;
#pragma unroll 8
    for (int i = 0; i < 64; ++i) {
        float2 xv = xs2[i * 64 + m];
        float wrv = wrp[(size_t)i * MMo];
        float wiv = wip[(size_t)i * MMo];
        are += xv.x * wrv - xv.y * wiv;
        aim += xv.x * wiv + xv.y * wrv;
    }
    float2* op = (float2*)(Of + ((size_t)b * HH + o) * 128);
    op[m] = make_float2(are, aim);
}

// ---------------------------------------------------------------------------
// Recon (layers 0..2): x_next[b][o][l] =
//   gelu( sum_k Of[b][o][k]*Trec[k][l] + sum_i wsk[o][i]*x[b][i][l] + bsk[o] )
// grid (32 l-tiles of 128, 32 b), block 256, tile 64 o x 128 l.
// ---------------------------------------------------------------------------
__global__ __launch_bounds__(256) void k_recon(const float* __restrict__ Of,
                                               const float* __restrict__ x,
                                               const float* __restrict__ Trec,
                                               const float* __restrict__ wsk,
                                               const float* __restrict__ bsk,
                                               float* __restrict__ xn, int layer) {
    __shared__ float Asl[64 * 132];   // phase1: Of (stride 132); phase2: wsk (stride 68)
    __shared__ float Bsl[32 * 128];
    const int t = threadIdx.x;
    const int b = blockIdx.y;
    const int l0 = blockIdx.x * 128;
    const int lsub = t & 15, osub = t >> 4;
    float acc[4][8];
#pragma unroll
    for (int j = 0; j < 4; ++j)
#pragma unroll
        for (int jj = 0; jj < 8; ++jj) acc[j][jj] = 0.0f;

    {   // A1 = Of[b] : 64 x 128 contiguous -> stride-132 LDS
        const float* src = Of + (size_t)b * HH * 128;
#pragma unroll
        for (int i = 0; i < 8; ++i) {
            int f = t * 4 + i * 1024;
            float4 v = CF4(src + f);
            int r = f >> 7, k = f & 127;
            F4(&Asl[r * 132 + k]) = v;
        }
    }
    // ---- phase 1: spectral reconstruction GEMM, K = 128
    for (int kc = 0; kc < 128; kc += 32) {
        __syncthreads();
#pragma unroll
        for (int i = 0; i < 4; ++i) {   // B: Trec rows kc..kc+31, cols l0..l0+127
            int f = t + i * 256;
            int r = f >> 5, c4 = f & 31;
            float4 v = CF4(Trec + (size_t)(kc + r) * LL + l0 + c4 * 4);
            F4(&Bsl[r * 128 + c4 * 4]) = v;
        }
        __syncthreads();
#pragma unroll 2
        for (int k4 = 0; k4 < 32; k4 += 4) {
            float va[4][4];
#pragma unroll
            for (int j = 0; j < 4; ++j) {
                float4 a = CF4(&Asl[(osub * 4 + j) * 132 + kc + k4]);
                va[j][0] = a.x; va[j][1] = a.y; va[j][2] = a.z; va[j][3] = a.w;
            }
#pragma unroll
            for (int dk = 0; dk < 4; ++dk) {
#pragma unroll
                for (int jj = 0; jj < 8; ++jj) {
                    float bv = Bsl[(k4 + dk) * 128 + lsub + 16 * jj];
                    acc[0][jj] += va[0][dk] * bv;
                    acc[1][jj] += va[1][dk] * bv;
                    acc[2][jj] += va[2][dk] * bv;
                    acc[3][jj] += va[3][dk] * bv;
                }
            }
        }
    }
    // ---- phase 2: skip GEMM, K = 64
    __syncthreads();
    {   // A2 = w_skip[layer] : 64 x 64 -> stride-68 LDS
        const float* src = wsk + (size_t)layer * HH * HH;
#pragma unroll
        for (int i = 0; i < 4; ++i) {
            int f = t * 4 + i * 1024;
            float4 v = CF4(src + f);
            int r = f >> 6, k = f & 63;
            F4(&Asl[r * 68 + k]) = v;
        }
    }
    for (int kc = 0; kc < 64; kc += 32) {
        __syncthreads();
#pragma unroll
        for (int i = 0; i < 4; ++i) {   // B: x[b] rows kc..kc+31, cols l0..l0+127
            int f = t + i * 256;
            int r = f >> 5, c4 = f & 31;
            float4 v = CF4(x + ((size_t)b * HH + kc + r) * LL + l0 + c4 * 4);
            F4(&Bsl[r * 128 + c4 * 4]) = v;
        }
        __syncthreads();
#pragma unroll 2
        for (int k4 = 0; k4 < 32; k4 += 4) {
            float va[4][4];
#pragma unroll
            for (int j = 0; j < 4; ++j) {
                float4 a = CF4(&Asl[(osub * 4 + j) * 68 + kc + k4]);
                va[j][0] = a.x; va[j][1] = a.y; va[j][2] = a.z; va[j][3] = a.w;
            }
#pragma unroll
            for (int dk = 0; dk < 4; ++dk) {
#pragma unroll
                for (int jj = 0; jj < 8; ++jj) {
                    float bv = Bsl[(k4 + dk) * 128 + lsub + 16 * jj];
                    acc[0][jj] += va[0][dk] * bv;
                    acc[1][jj] += va[1][dk] * bv;
                    acc[2][jj] += va[2][dk] * bv;
                    acc[3][jj] += va[3][dk] * bv;
                }
            }
        }
    }
    // ---- epilogue: bias + gelu + store
    const float* bp = bsk + (size_t)layer * HH;
#pragma unroll
    for (int j = 0; j < 4; ++j) {
        float bias = bp[osub * 4 + j];
        float* op = xn + ((size_t)b * HH + osub * 4 + j) * LL + l0;
#pragma unroll
        for (int jj = 0; jj < 8; ++jj)
            op[lsub + 16 * jj] = gelu_tanh(acc[j][jj] + bias);
    }
}

// ---------------------------------------------------------------------------
// Final layer (i=3) + projection, only l = L-1 needed. grid 32 (b), block 128.
// OUTPUT IS FLOAT32 (reference output dtype) — round-1 failure was writing bf16.
// ---------------------------------------------------------------------------
__global__ __launch_bounds__(128) void k_final(const float* __restrict__ Of,
                                               const float* __restrict__ x3,
                                               const float* __restrict__ Trec,
                                               const float* __restrict__ wsk,
                                               const float* __restrict__ bsk,
                                               const float* __restrict__ wp1,
                                               const float* __restrict__ bp1,
                                               const float* __restrict__ wp2,
                                               const float* __restrict__ bp2,
                                               float* __restrict__ out) {
    __shared__ float tl[128], xl[64], x4[64], y[128];
    const int b = blockIdx.x, t = threadIdx.x;
    tl[t] = Trec[(size_t)t * LL + (LL - 1)];
    if (t < 64) xl[t] = x3[((size_t)b * HH + t) * LL + (LL - 1)];
    __syncthreads();
    if (t < 64) {
        const int o = t;
        float acc = bsk[3 * HH + o];
        const float* ofp = Of + ((size_t)b * HH + o) * 128;
        for (int k = 0; k < 128; ++k) acc += ofp[k] * tl[k];
        const float* wp = wsk + (size_t)(3 * HH + o) * HH;
        for (int i = 0; i < 64; ++i) acc += wp[i] * xl[i];
        x4[o] = acc;   // no gelu after last FNO layer
    }
    __syncthreads();
    {
        float acc = bp1[t];
        for (int h = 0; h < 64; ++h) acc += wp1[t * 64 + h] * x4[h];
        y[t] = gelu_tanh(acc);
    }
    __syncthreads();
    if (t < 8) {
        float acc = bp2[t];
        for (int p = 0; p < 128; ++p) acc += wp2[t * 128 + p] * y[p];
        out[b * 8 + t] = acc;   // float32 store
    }
}

// ---------------------------------------------------------------------------
extern "C" void kernel_launch(void* const* d_in, const int* in_sizes, int n_in,
                              void* d_out, int out_size, void* d_ws, size_t ws_size,
                              hipStream_t stream) {
    (void)in_sizes; (void)n_in; (void)out_size; (void)ws_size;
    const float* u   = (const float*)d_in[0];
    const float* z   = (const float*)d_in[1];
    // d_in[2] = t, unused by the reference
    const float* wl  = (const float*)d_in[3];
    const float* bl  = (const float*)d_in[4];
    const float* swr = (const float*)d_in[5];
    const float* swi = (const float*)d_in[6];
    const float* wsk = (const float*)d_in[7];
    const float* bsk = (const float*)d_in[8];
    const float* wp1 = (const float*)d_in[9];
    const float* bp1 = (const float*)d_in[10];
    const float* wp2 = (const float*)d_in[11];
    const float* bp2 = (const float*)d_in[12];
    float* out = (float*)d_out;

    float* ws   = (float*)d_ws;
    float* X0   = ws;                    // 8,388,608 floats (32 MB)
    float* X1   = X0 + 8388608;          // 8,388,608
    float* Tdft = X1 + 8388608;          //   524,288  [l][128]
    float* Trec = Tdft + 524288;         //   524,288  [m2][l]
    float* Xf   = Trec + 524288;         //   262,144  [(b,h)][m2]
    float* Of   = Xf + 262144;           //   262,144  [(b,o)][m2]
    // total: 18,350,080 floats = 73.4 MB. Y partials (8 MB) overlay `nxt`.

    k_twiddle<<<1024, 256, 0, stream>>>(Tdft, Trec);
    k_lift<<<dim3(16, 32), 256, 0, stream>>>(u, z, wl, bl, X0);

    float* cur = X0;
    float* nxt = X1;
    for (int layer = 0; layer < 4; ++layer) {
        float* Y = nxt;  // dead region: recon only writes nxt after Y consumed
        k_dft<<<dim3(32, 8), 256, 0, stream>>>(cur, Tdft, Y);
        k_redY<<<1024, 256, 0, stream>>>(Y, Xf);
        k_spec<<<dim3(16, 32), 256, 0, stream>>>(Xf, swr, swi, Of, layer);
        if (layer < 3) {
            k_recon<<<dim3(32, 32), 256, 0, stream>>>(Of, cur, Trec, wsk, bsk, nxt, layer);
            float* tmp = cur; cur = nxt; nxt = tmp;
        } else {
            k_final<<<32, 128, 0, stream>>>(Of, cur, Trec, wsk, bsk,
                                            wp1, bp1, wp2, bp2, out);
        }
    }
}

// Round 3
// 326.849 us; speedup vs baseline: 1.5910x; 1.5910x over previous
//
#include <hip/hip_runtime.h>
#include <math.h>

typedef _Float16 f16;
typedef f16  f16x8 __attribute__((ext_vector_type(8)));
typedef float f32x4 __attribute__((ext_vector_type(4)));

#define F4(p)  (*(float4*)(p))
#define CF4(p) (*(const float4*)(p))

namespace {
constexpr int LL = 4096;   // sequence
constexpr int HH = 64;     // channels

__device__ __forceinline__ float gelu_tanh(float x) {
    // jax.nn.gelu approximate=True
    float inner = 0.7978845608028654f * (x + 0.044715f * x * x * x);
    return 0.5f * x * (1.0f + tanhf(inner));
}

__device__ __forceinline__ f32x4 mfma16(f16x8 a, f16x8 b, f32x4 c) {
    return __builtin_amdgcn_mfma_f32_16x16x32_f16(a, b, c, 0, 0, 0);
}
} // namespace

// ---------------------------------------------------------------------------
// Twiddle tables (fp16) + w_skip fp16 conversion.
//   Tdt[m2][l]  (m2 = 2m re / 2m+1 im):  cos(2pi m l/L), -sin(2pi m l/L)
//   Ttr[l][m2]: (m==0 ? 1 : 2cos)/L, (m==0 ? 0 : -2sin)/L   (irfft weights)
// ---------------------------------------------------------------------------
__global__ __launch_bounds__(256) void k_twiddle(f16* __restrict__ Tdt,
                                                 f16* __restrict__ Ttr,
                                                 const float* __restrict__ wsk,
                                                 f16* __restrict__ wskh) {
    int idx = blockIdx.x * 256 + threadIdx.x;   // 0 .. 262143
    int l = idx >> 6, m = idx & 63;
    float ang = (float)((l * m) & 4095) * (6.283185307179586f / 4096.0f);
    float s, c;
    sincosf(ang, &s, &c);
    Tdt[(size_t)(2 * m) * LL + l]     = (f16)c;
    Tdt[(size_t)(2 * m + 1) * LL + l] = (f16)(-s);
    const float sc = 1.0f / 4096.0f;
    Ttr[(size_t)l * 128 + 2 * m]     = (f16)((m == 0) ? sc : 2.0f * sc * c);
    Ttr[(size_t)l * 128 + 2 * m + 1] = (f16)((m == 0) ? 0.0f : -2.0f * sc * s);
    if (idx < 4 * HH * HH) wskh[idx] = (f16)wsk[idx];
}

// ---------------------------------------------------------------------------
// Lift: writes BOTH layouts: x0[b][h][l] and xt0[b][l][h]  (fp16)
// ---------------------------------------------------------------------------
__global__ __launch_bounds__(256) void k_lift(const float* __restrict__ u,
                                              const float* __restrict__ z,
                                              const float* __restrict__ wl,
                                              const float* __restrict__ bl,
                                              f16* __restrict__ x0,
                                              f16* __restrict__ xt0) {
    __shared__ float wsh[64 * 16];
    __shared__ float bsh[64];
    const int t = threadIdx.x;
    for (int i = t; i < 1024; i += 256) wsh[i] = wl[i];
    if (t < 64) bsh[t] = bl[t];
    __syncthreads();
    const int b = blockIdx.y;
    const int l = blockIdx.x * 256 + t;
    float in[16];
    const float* up = u + ((size_t)b * LL + l) * 8;
#pragma unroll
    for (int c = 0; c < 8; ++c) in[c] = up[c];
#pragma unroll
    for (int c = 0; c < 8; ++c) in[8 + c] = z[b * 8 + c];
    __attribute__((aligned(16))) f16 harr[64];
    for (int h = 0; h < 64; ++h) {
        float acc = bsh[h];
#pragma unroll
        for (int c = 0; c < 16; ++c) acc += wsh[h * 16 + c] * in[c];
        f16 hv = (f16)acc;
        harr[h] = hv;
        x0[((size_t)(b * HH + h)) * LL + l] = hv;
    }
    f16x8* dst = (f16x8*)(xt0 + ((size_t)b * LL + l) * HH);
    const f16x8* src = (const f16x8*)harr;
#pragma unroll
    for (int i = 0; i < 8; ++i) dst[i] = src[i];
}

// ---------------------------------------------------------------------------
// Partial DFT, fp16 MFMA: Y[ch][(b,h)][m2] = sum_{l in 512-chunk} x[b][h][l]*Tdt[m2][l]
// grid (8 ch, 32 b), block 256 (4 waves). Block tile 64 h x 128 m2, K=512.
// ---------------------------------------------------------------------------
__global__ __launch_bounds__(256) void k_dft(const f16* __restrict__ x,
                                             const f16* __restrict__ Tdt,
                                             float* __restrict__ Y) {
    __shared__ f16 Asl[64 * 72];    // [h][k] pitch 72
    __shared__ f16 Bsl[128 * 72];   // [m2][k] pitch 72
    const int t = threadIdx.x;
    const int ch = blockIdx.x, b = blockIdx.y;
    const int lane = t & 63, wid = t >> 6;
    const int m0 = (wid >> 1) * 32, n0 = (wid & 1) * 64;
    const int fm = lane & 15, fq = lane >> 4;
    const int srow = t >> 3, sseg = t & 7;
    f32x4 acc[2][4] = {};
    for (int k0 = 0; k0 < 512; k0 += 64) {
        const int l0 = ch * 512 + k0;
        __syncthreads();
#pragma unroll
        for (int p = 0; p < 2; ++p) {   // A: x[b][h][l0..l0+63]
            int r = srow + p * 32;
            F4(&Asl[r * 72 + sseg * 8]) = CF4(x + ((size_t)(b * HH + r)) * LL + l0 + sseg * 8);
        }
#pragma unroll
        for (int p = 0; p < 4; ++p) {   // B: Tdt[m2][l0..l0+63]
            int r = srow + p * 32;
            F4(&Bsl[r * 72 + sseg * 8]) = CF4(Tdt + (size_t)r * LL + l0 + sseg * 8);
        }
        __syncthreads();
#pragma unroll
        for (int ks = 0; ks < 64; ks += 32) {
            f16x8 a0 = *(const f16x8*)&Asl[(m0 + fm) * 72 + ks + fq * 8];
            f16x8 a1 = *(const f16x8*)&Asl[(m0 + 16 + fm) * 72 + ks + fq * 8];
#pragma unroll
            for (int j = 0; j < 4; ++j) {
                f16x8 bj = *(const f16x8*)&Bsl[(n0 + j * 16 + fm) * 72 + ks + fq * 8];
                acc[0][j] = mfma16(a0, bj, acc[0][j]);
                acc[1][j] = mfma16(a1, bj, acc[1][j]);
            }
        }
    }
    float* yp = Y + ((size_t)ch * 2048 + b * HH) * 128;
#pragma unroll
    for (int i = 0; i < 2; ++i)
#pragma unroll
        for (int j = 0; j < 4; ++j)
#pragma unroll
            for (int r = 0; r < 4; ++r)
                yp[(size_t)(m0 + i * 16 + fq * 4 + r) * 128 + n0 + j * 16 + fm] = acc[i][j][r];
}

// Reduce split-K partials: Xf = sum_ch Y[ch]   (fp32)
__global__ __launch_bounds__(256) void k_redY(const float* __restrict__ Y,
                                              float* __restrict__ Xf) {
    int idx = blockIdx.x * 256 + threadIdx.x;   // < 262144
    float s = 0.0f;
#pragma unroll
    for (int c = 0; c < 8; ++c) s += Y[(size_t)c * 262144 + idx];
    Xf[idx] = s;
}

// ---------------------------------------------------------------------------
// Spectral mix (fp32 math, fp16 output): Of[b][o][m2]
// ---------------------------------------------------------------------------
__global__ __launch_bounds__(256) void k_spec(const float* __restrict__ Xf,
                                              const float* __restrict__ wr,
                                              const float* __restrict__ wi,
                                              f16* __restrict__ Ofh, int layer) {
    __shared__ float xsh[64 * 128];
    const int t = threadIdx.x;
    const int b = blockIdx.y;
    const int og = blockIdx.x;
    {
        const float4* src = (const float4*)(Xf + (size_t)b * HH * 128);
        float4* dst = (float4*)xsh;
#pragma unroll
        for (int i = 0; i < 8; ++i) dst[t + i * 256] = src[t + i * 256];
    }
    __syncthreads();
    const int m = t & 63, osub = t >> 6;
    const int o = og * 4 + osub;
    const float* wrp = wr + ((size_t)layer * HH + o) * HH * 64 + m;
    const float* wip = wi + ((size_t)layer * HH + o) * HH * 64 + m;
    float are = 0.0f, aim = 0.0f;
    const float2* xs2 = (const float2*)xsh;
#pragma unroll 8
    for (int i = 0; i < 64; ++i) {
        float2 xv = xs2[i * 64 + m];
        float wrv = wrp[(size_t)i * 64];
        float wiv = wip[(size_t)i * 64];
        are += xv.x * wrv - xv.y * wiv;
        aim += xv.x * wiv + xv.y * wrv;
    }
    f16* op = Ofh + ((size_t)b * HH + o) * 128;
    op[2 * m]     = (f16)are;
    op[2 * m + 1] = (f16)aim;
}

// ---------------------------------------------------------------------------
// Recon (layers 0..2), fp16 MFMA, fused K=192 = [Of | Wsk] x [Ttr ; X^T]:
//   x_next[b][o][l] = gelu( sum_k A[o][k]*B[k][l] + bsk[o] )
// Writes x_next[o][l] and (layers 0,1) XT_next[l][o] via LDS transpose.
// grid (32 l-tiles of 128, 32 b), block 256 (4 waves), tile 64 o x 128 l.
// ---------------------------------------------------------------------------
__global__ __launch_bounds__(256) void k_recon(const f16* __restrict__ Ofh,
                                               const f16* __restrict__ XT,
                                               const f16* __restrict__ Ttr,
                                               const f16* __restrict__ wskh,
                                               const float* __restrict__ bsk,
                                               f16* __restrict__ xn,
                                               f16* __restrict__ XTn,
                                               int layer, int write_xt) {
    __shared__ f16 Asl[64 * 200];   // [o][k0..191], pitch 200
    __shared__ f16 Bsl[128 * 72];   // [l][k-chunk], pitch 72; reused as XT staging
    const int t = threadIdx.x;
    const int l0 = blockIdx.x * 128, b = blockIdx.y;
    const int lane = t & 63, wid = t >> 6;
    const int m0 = (wid & 1) * 32, n0 = (wid >> 1) * 64;
    const int fm = lane & 15, fq = lane >> 4;
    f32x4 acc[2][4] = {};
    {   // stage A = [Of[b] | wskh[layer]]
        int seg = t & 15, row = t >> 4;
#pragma unroll
        for (int p = 0; p < 4; ++p) {
            int r = row + p * 16;
            F4(&Asl[r * 200 + seg * 8]) = CF4(Ofh + ((size_t)(b * HH + r)) * 128 + seg * 8);
        }
        int seg8 = t & 7, row8 = t >> 3;
#pragma unroll
        for (int p = 0; p < 2; ++p) {
            int r = row8 + p * 32;
            F4(&Asl[r * 200 + 128 + seg8 * 8]) =
                CF4(wskh + ((size_t)(layer * HH + r)) * HH + seg8 * 8);
        }
    }
    const int srow = t >> 3, sseg = t & 7;
    for (int k0 = 0; k0 < 192; k0 += 64) {
        __syncthreads();
#pragma unroll
        for (int p = 0; p < 4; ++p) {   // B rows l: Ttr[l][k0..] or XT[b][l][h]
            int r = srow + p * 32;
            const f16* src = (k0 < 128)
                ? (Ttr + (size_t)(l0 + r) * 128 + k0 + sseg * 8)
                : (XT + ((size_t)b * LL + l0 + r) * HH + sseg * 8);
            F4(&Bsl[r * 72 + sseg * 8]) = CF4(src);
        }
        __syncthreads();
#pragma unroll
        for (int ks = 0; ks < 64; ks += 32) {
            f16x8 a0 = *(const f16x8*)&Asl[(m0 + fm) * 200 + k0 + ks + fq * 8];
            f16x8 a1 = *(const f16x8*)&Asl[(m0 + 16 + fm) * 200 + k0 + ks + fq * 8];
#pragma unroll
            for (int j = 0; j < 4; ++j) {
                f16x8 bj = *(const f16x8*)&Bsl[(n0 + j * 16 + fm) * 72 + ks + fq * 8];
                acc[0][j] = mfma16(a0, bj, acc[0][j]);
                acc[1][j] = mfma16(a1, bj, acc[1][j]);
            }
        }
    }
    __syncthreads();   // Bsl frag reads done; safe to reuse as XT staging
    // epilogue: bias + gelu; write x_next[o][l]; stash fp16 into Bsl as [l][o]
#pragma unroll
    for (int i = 0; i < 2; ++i)
#pragma unroll
        for (int r = 0; r < 4; ++r) {
            int row = m0 + i * 16 + fq * 4 + r;
            float bias = bsk[layer * HH + row];
#pragma unroll
            for (int j = 0; j < 4; ++j) {
                float v = gelu_tanh(acc[i][j][r] + bias);
                f16 hv = (f16)v;
                int lc = n0 + j * 16 + fm;
                xn[((size_t)(b * HH + row)) * LL + l0 + lc] = hv;
                Bsl[lc * 72 + row] = hv;
            }
        }
    if (write_xt) {
        __syncthreads();
        int row = t >> 1, half = t & 1;
        f16* dst = XTn + ((size_t)b * LL + l0 + row) * HH + half * 32;
        const f16* src = &Bsl[row * 72 + half * 32];
#pragma unroll
        for (int i = 0; i < 4; ++i)
            F4(dst + i * 8) = CF4(src + i * 8);
    }
}

// ---------------------------------------------------------------------------
// Final layer (i=3) + projection, only l = L-1. grid 32 (b), block 128.
// ---------------------------------------------------------------------------
__global__ __launch_bounds__(128) void k_final(const f16* __restrict__ Ofh,
                                               const f16* __restrict__ x3,
                                               const f16* __restrict__ Ttr,
                                               const float* __restrict__ wsk,
                                               const float* __restrict__ bsk,
                                               const float* __restrict__ wp1,
                                               const float* __restrict__ bp1,
                                               const float* __restrict__ wp2,
                                               const float* __restrict__ bp2,
                                               float* __restrict__ out) {
    __shared__ float tl[128], xl[64], x4[64], y[128];
    const int b = blockIdx.x, t = threadIdx.x;
    tl[t] = (float)Ttr[(size_t)(LL - 1) * 128 + t];
    if (t < 64) xl[t] = (float)x3[((size_t)(b * HH + t)) * LL + (LL - 1)];
    __syncthreads();
    if (t < 64) {
        const int o = t;
        float acc = bsk[3 * HH + o];
        const f16* ofp = Ofh + ((size_t)(b * HH + o)) * 128;
        for (int k = 0; k < 128; ++k) acc += (float)ofp[k] * tl[k];
        const float* wp = wsk + (size_t)(3 * HH + o) * HH;
        for (int i = 0; i < 64; ++i) acc += wp[i] * xl[i];
        x4[o] = acc;   // no gelu after last FNO layer
    }
    __syncthreads();
    {
        float acc = bp1[t];
        for (int h = 0; h < 64; ++h) acc += wp1[t * 64 + h] * x4[h];
        y[t] = gelu_tanh(acc);
    }
    __syncthreads();
    if (t < 8) {
        float acc = bp2[t];
        for (int p = 0; p < 128; ++p) acc += wp2[t * 128 + p] * y[p];
        out[b * 8 + t] = acc;   // float32 output
    }
}

// ---------------------------------------------------------------------------
extern "C" void kernel_launch(void* const* d_in, const int* in_sizes, int n_in,
                              void* d_out, int out_size, void* d_ws, size_t ws_size,
                              hipStream_t stream) {
    (void)in_sizes; (void)n_in; (void)out_size; (void)ws_size;
    const float* u   = (const float*)d_in[0];
    const float* z   = (const float*)d_in[1];
    // d_in[2] = t, unused by the reference
    const float* wl  = (const float*)d_in[3];
    const float* bl  = (const float*)d_in[4];
    const float* swr = (const float*)d_in[5];
    const float* swi = (const float*)d_in[6];
    const float* wsk = (const float*)d_in[7];
    const float* bsk = (const float*)d_in[8];
    const float* wp1 = (const float*)d_in[9];
    const float* bp1 = (const float*)d_in[10];
    const float* wp2 = (const float*)d_in[11];
    const float* bp2 = (const float*)d_in[12];
    float* out = (float*)d_out;

    // fp16 workspace layout (element counts are halves unless noted)
    f16* ws    = (f16*)d_ws;
    f16* x0h   = ws;                  // 8,388,608 h (16 MB)
    f16* x1h   = x0h + 8388608;       // 8,388,608 h
    f16* XTa   = x1h + 8388608;       // 8,388,608 h  [b][l][h]
    f16* XTb   = XTa + 8388608;       // 8,388,608 h
    f16* Tdt   = XTb + 8388608;       //   524,288 h  [m2][l]
    f16* Ttr   = Tdt + 524288;        //   524,288 h  [l][m2]
    f16* Ofh   = Ttr + 524288;        //   262,144 h  [b][o][m2]
    f16* wskh  = Ofh + 262144;        //    16,384 h
    float* Xf  = (float*)(wskh + 16384);  // 262,144 f (1 MB)
    // total ~ 68.5 MB.  Y (8 MB fp32 partials) overlays the dead next-x buffer.

    k_twiddle<<<1024, 256, 0, stream>>>(Tdt, Ttr, wsk, wskh);
    k_lift<<<dim3(16, 32), 256, 0, stream>>>(u, z, wl, bl, x0h, XTa);

    f16* xc = x0h; f16* xn = x1h;
    f16* xtc = XTa; f16* xtn = XTb;
    for (int layer = 0; layer < 4; ++layer) {
        float* Y = (float*)xn;   // dead until recon writes it (after redY consumed Y)
        k_dft<<<dim3(8, 32), 256, 0, stream>>>(xc, Tdt, Y);
        k_redY<<<1024, 256, 0, stream>>>(Y, Xf);
        k_spec<<<dim3(16, 32), 256, 0, stream>>>(Xf, swr, swi, Ofh, layer);
        if (layer < 3) {
            k_recon<<<dim3(32, 32), 256, 0, stream>>>(Ofh, xtc, Ttr, wskh, bsk,
                                                      xn, xtn, layer, layer < 2 ? 1 : 0);
            f16* tmp = xc; xc = xn; xn = tmp;
            tmp = xtc; xtc = xtn; xtn = tmp;
        } else {
            k_final<<<32, 128, 0, stream>>>(Ofh, xc, Ttr, wsk, bsk,
                                            wp1, bp1, wp2, bp2, out);
        }
    }
}

// Round 4
// 263.827 us; speedup vs baseline: 1.9710x; 1.2389x over previous
//
#include <hip/hip_runtime.h>
#include <math.h>

typedef _Float16 f16;
typedef f16  f16x8 __attribute__((ext_vector_type(8)));
typedef float f32x4 __attribute__((ext_vector_type(4)));

#define F4(p)  (*(float4*)(p))
#define CF4(p) (*(const float4*)(p))

namespace {
constexpr int LL = 4096;   // sequence
constexpr int HH = 64;     // channels

__device__ __forceinline__ float gelu_tanh(float x) {
    // jax.nn.gelu approximate=True
    float inner = 0.7978845608028654f * (x + 0.044715f * x * x * x);
    return 0.5f * x * (1.0f + tanhf(inner));
}

__device__ __forceinline__ f32x4 mfma16(f16x8 a, f16x8 b, f32x4 c) {
    return __builtin_amdgcn_mfma_f32_16x16x32_f16(a, b, c, 0, 0, 0);
}
} // namespace

// ---------------------------------------------------------------------------
// Twiddle tables (fp16) + w_skip fp16 conversion.
//   Tdt[m2][l]:  cos(2pi m l/L), -sin(2pi m l/L)      (DFT weights)
//   Ttr[l][m2]: (m==0?1:2cos)/L, (m==0?0:-2sin)/L     (irfft weights, Im(a0) drop)
// ---------------------------------------------------------------------------
__global__ __launch_bounds__(256) void k_twiddle(f16* __restrict__ Tdt,
                                                 f16* __restrict__ Ttr,
                                                 const float* __restrict__ wsk,
                                                 f16* __restrict__ wskh) {
    int idx = blockIdx.x * 256 + threadIdx.x;   // 0 .. 262143
    int l = idx >> 6, m = idx & 63;
    float ang = (float)((l * m) & 4095) * (6.283185307179586f / 4096.0f);
    float s, c;
    sincosf(ang, &s, &c);
    Tdt[(size_t)(2 * m) * LL + l]     = (f16)c;
    Tdt[(size_t)(2 * m + 1) * LL + l] = (f16)(-s);
    const float sc = 1.0f / 4096.0f;
    Ttr[(size_t)l * 128 + 2 * m]     = (f16)((m == 0) ? sc : 2.0f * sc * c);
    Ttr[(size_t)l * 128 + 2 * m + 1] = (f16)((m == 0) ? 0.0f : -2.0f * sc * s);
    if (idx < 4 * HH * HH) wskh[idx] = (f16)wsk[idx];
}

// ---------------------------------------------------------------------------
// Lift v2: XT0[b][l][h] only. Register-tiled 8h x 8l per thread.
// grid (16 l-tiles of 256, 32 b), block 256.
// ---------------------------------------------------------------------------
__global__ __launch_bounds__(256) void k_lift(const float* __restrict__ u,
                                              const float* __restrict__ z,
                                              const float* __restrict__ wl,
                                              const float* __restrict__ bl,
                                              f16* __restrict__ XT0) {
    constexpr int IP = 260;           // in_s pitch (floats)
    __shared__ float in_s[16 * IP];   // [c][l-tile 256]
    __shared__ float wsh[64 * 16];
    __shared__ float bsh[64];
    const int t = threadIdx.x;
    const int b = blockIdx.y;
    const int l0 = blockIdx.x * 256;
    for (int i = t; i < 1024; i += 256) wsh[i] = wl[i];
    if (t < 64) bsh[t] = bl[t];
    {   // stage u tile transposed: u[b][l0+l][c] -> in_s[c][l]
#pragma unroll
        for (int q = 0; q < 2; ++q) {
            int f = t + q * 256;
            int l = f >> 1, cq = (f & 1) * 4;
            float4 v = CF4(u + ((size_t)b * LL + l0 + l) * 8 + cq);
            in_s[(cq + 0) * IP + l] = v.x;
            in_s[(cq + 1) * IP + l] = v.y;
            in_s[(cq + 2) * IP + l] = v.z;
            in_s[(cq + 3) * IP + l] = v.w;
        }
        for (int f = t; f < 8 * 256; f += 256) {   // z broadcast rows
            int c = f >> 8, l = f & 255;
            in_s[(8 + c) * IP + l] = z[b * 8 + c];
        }
    }
    __syncthreads();
    const int hg = t >> 5, lsub = t & 31;   // 8 h's, 8 l's (stride 32)
    float acc[8][8] = {};
    for (int c = 0; c < 16; ++c) {
        float wv[8], inv[8];
#pragma unroll
        for (int i = 0; i < 8; ++i) wv[i] = wsh[(hg * 8 + i) * 16 + c];
#pragma unroll
        for (int j = 0; j < 8; ++j) inv[j] = in_s[c * IP + lsub + 32 * j];
#pragma unroll
        for (int i = 0; i < 8; ++i)
#pragma unroll
            for (int j = 0; j < 8; ++j) acc[i][j] += wv[i] * inv[j];
    }
#pragma unroll
    for (int j = 0; j < 8; ++j) {
        __attribute__((aligned(16))) f16 hv[8];
#pragma unroll
        for (int i = 0; i < 8; ++i) hv[i] = (f16)(acc[i][j] + bsh[hg * 8 + i]);
        int l = l0 + lsub + 32 * j;
        F4(XT0 + ((size_t)b * LL + l) * HH + hg * 8) = CF4(hv);
    }
}

// ---------------------------------------------------------------------------
// Partial DFT, fp16 MFMA, consumes XT[b][l][h] (transpose-staged in LDS):
//   Y[ch][(b,h)][m2] = sum_{l in 512-chunk} XT[b][l][h] * Tdt[m2][l]
// grid (8 ch, 32 b), block 256 (4 waves). Tile 64 h x 128 m2, K=512.
// ---------------------------------------------------------------------------
__global__ __launch_bounds__(256) void k_dft(const f16* __restrict__ XT,
                                             const f16* __restrict__ Tdt,
                                             float* __restrict__ Y) {
    __shared__ f16 Asl[64 * 72];    // [h][l-chunk] pitch 72
    __shared__ f16 Bsl[128 * 72];   // [m2][l-chunk] pitch 72
    const int t = threadIdx.x;
    const int ch = blockIdx.x, b = blockIdx.y;
    const int lane = t & 63, wid = t >> 6;
    const int m0 = (wid >> 1) * 32, n0 = (wid & 1) * 64;
    const int fm = lane & 15, fq = lane >> 4;
    const int srow = t >> 3, sseg = t & 7;
    f32x4 acc[2][4] = {};
    for (int k0 = 0; k0 < 512; k0 += 64) {
        const int l0 = ch * 512 + k0;
        __syncthreads();
#pragma unroll
        for (int p = 0; p < 2; ++p) {   // A: XT rows -> transposed into Asl[h][l]
            int seg = wid + p * 4;      // h-segment (8 h's)
            f16x8 v = *(const f16x8*)(XT + ((size_t)b * LL + l0 + lane) * HH + seg * 8);
#pragma unroll
            for (int i = 0; i < 8; ++i)
                Asl[(seg * 8 + i) * 72 + lane] = v[i];   // lane-contiguous: free
        }
#pragma unroll
        for (int p = 0; p < 4; ++p) {   // B: Tdt[m2][l0..l0+63]
            int r = srow + p * 32;
            F4(&Bsl[r * 72 + sseg * 8]) = CF4(Tdt + (size_t)r * LL + l0 + sseg * 8);
        }
        __syncthreads();
#pragma unroll
        for (int ks = 0; ks < 64; ks += 32) {
            f16x8 a0 = *(const f16x8*)&Asl[(m0 + fm) * 72 + ks + fq * 8];
            f16x8 a1 = *(const f16x8*)&Asl[(m0 + 16 + fm) * 72 + ks + fq * 8];
#pragma unroll
            for (int j = 0; j < 4; ++j) {
                f16x8 bj = *(const f16x8*)&Bsl[(n0 + j * 16 + fm) * 72 + ks + fq * 8];
                acc[0][j] = mfma16(a0, bj, acc[0][j]);
                acc[1][j] = mfma16(a1, bj, acc[1][j]);
            }
        }
    }
    float* yp = Y + ((size_t)ch * 2048 + b * HH) * 128;
#pragma unroll
    for (int i = 0; i < 2; ++i)
#pragma unroll
        for (int j = 0; j < 4; ++j)
#pragma unroll
            for (int r = 0; r < 4; ++r)
                yp[(size_t)(m0 + i * 16 + fq * 4 + r) * 128 + n0 + j * 16 + fm] = acc[i][j][r];
}

// ---------------------------------------------------------------------------
// Spectral mix, fused split-K reduction (sums the 8 Y chunks in-staging, same
// order as the old redY -> bitwise identical). fp32 math, fp16 out.
// grid (16 o-groups, 32 b), block 256.
// ---------------------------------------------------------------------------
__global__ __launch_bounds__(256) void k_spec(const float* __restrict__ Y,
                                              const float* __restrict__ wr,
                                              const float* __restrict__ wi,
                                              f16* __restrict__ Ofh, int layer) {
    __shared__ float xsh[64 * 128];
    const int t = threadIdx.x;
    const int b = blockIdx.y;
    const int og = blockIdx.x;
    {   // stage Xf[b] = sum_ch Y[ch][b]
        float4* dst = (float4*)xsh;
        const float* base = Y + (size_t)b * 8192;
#pragma unroll
        for (int i = 0; i < 8; ++i) {
            int idx = t + i * 256;
            float4 s = CF4(base + (size_t)idx * 4);
#pragma unroll
            for (int c = 1; c < 8; ++c) {
                float4 v = CF4(base + (size_t)c * 262144 + (size_t)idx * 4);
                s.x += v.x; s.y += v.y; s.z += v.z; s.w += v.w;
            }
            dst[idx] = s;
        }
    }
    __syncthreads();
    const int m = t & 63, osub = t >> 6;
    const int o = og * 4 + osub;
    const float* wrp = wr + ((size_t)layer * HH + o) * HH * 64 + m;
    const float* wip = wi + ((size_t)layer * HH + o) * HH * 64 + m;
    float are = 0.0f, aim = 0.0f;
    const float2* xs2 = (const float2*)xsh;
#pragma unroll 8
    for (int i = 0; i < 64; ++i) {
        float2 xv = xs2[i * 64 + m];
        float wrv = wrp[(size_t)i * 64];
        float wiv = wip[(size_t)i * 64];
        are += xv.x * wrv - xv.y * wiv;
        aim += xv.x * wiv + xv.y * wrv;
    }
    f16* op = Ofh + ((size_t)b * HH + o) * 128;
    op[2 * m]     = (f16)are;
    op[2 * m + 1] = (f16)aim;
}

// ---------------------------------------------------------------------------
// Recon (layers 0..2), fp16 MFMA, fused K=192 = [Of | Wsk] x [Ttr ; X^T]:
//   x_next[b][o][l] = gelu( sum_k A[o][k]*B[k][l] + bsk[o] )
// Output ONLY in transposed layout XTn[b][l][o] (via LDS transpose).
// grid (32 l-tiles of 128, 32 b), block 256 (4 waves), tile 64 o x 128 l.
// ---------------------------------------------------------------------------
__global__ __launch_bounds__(256) void k_recon(const f16* __restrict__ Ofh,
                                               const f16* __restrict__ XT,
                                               const f16* __restrict__ Ttr,
                                               const f16* __restrict__ wskh,
                                               const float* __restrict__ bsk,
                                               f16* __restrict__ XTn,
                                               int layer) {
    __shared__ f16 Asl[64 * 200];   // [o][k 0..191], pitch 200
    __shared__ f16 Bsl[128 * 72];   // [l][k-chunk], pitch 72; reused for transpose
    const int t = threadIdx.x;
    const int l0 = blockIdx.x * 128, b = blockIdx.y;
    const int lane = t & 63, wid = t >> 6;
    const int m0 = (wid & 1) * 32, n0 = (wid >> 1) * 64;
    const int fm = lane & 15, fq = lane >> 4;
    f32x4 acc[2][4] = {};
    {   // stage A = [Of[b] | wskh[layer]]
        int seg = t & 15, row = t >> 4;
#pragma unroll
        for (int p = 0; p < 4; ++p) {
            int r = row + p * 16;
            F4(&Asl[r * 200 + seg * 8]) = CF4(Ofh + ((size_t)(b * HH + r)) * 128 + seg * 8);
        }
        int seg8 = t & 7, row8 = t >> 3;
#pragma unroll
        for (int p = 0; p < 2; ++p) {
            int r = row8 + p * 32;
            F4(&Asl[r * 200 + 128 + seg8 * 8]) =
                CF4(wskh + ((size_t)(layer * HH + r)) * HH + seg8 * 8);
        }
    }
    const int srow = t >> 3, sseg = t & 7;
    for (int k0 = 0; k0 < 192; k0 += 64) {
        __syncthreads();
#pragma unroll
        for (int p = 0; p < 4; ++p) {   // B rows l: Ttr[l][k0..] or XT[b][l][h]
            int r = srow + p * 32;
            const f16* src = (k0 < 128)
                ? (Ttr + (size_t)(l0 + r) * 128 + k0 + sseg * 8)
                : (XT + ((size_t)b * LL + l0 + r) * HH + sseg * 8);
            F4(&Bsl[r * 72 + sseg * 8]) = CF4(src);
        }
        __syncthreads();
#pragma unroll
        for (int ks = 0; ks < 64; ks += 32) {
            f16x8 a0 = *(const f16x8*)&Asl[(m0 + fm) * 200 + k0 + ks + fq * 8];
            f16x8 a1 = *(const f16x8*)&Asl[(m0 + 16 + fm) * 200 + k0 + ks + fq * 8];
#pragma unroll
            for (int j = 0; j < 4; ++j) {
                f16x8 bj = *(const f16x8*)&Bsl[(n0 + j * 16 + fm) * 72 + ks + fq * 8];
                acc[0][j] = mfma16(a0, bj, acc[0][j]);
                acc[1][j] = mfma16(a1, bj, acc[1][j]);
            }
        }
    }
    __syncthreads();   // frag reads done; reuse Bsl as [l][o] staging
#pragma unroll
    for (int i = 0; i < 2; ++i)
#pragma unroll
        for (int r = 0; r < 4; ++r) {
            int row = m0 + i * 16 + fq * 4 + r;
            float bias = bsk[layer * HH + row];
#pragma unroll
            for (int j = 0; j < 4; ++j) {
                float v = gelu_tanh(acc[i][j][r] + bias);
                int lc = n0 + j * 16 + fm;
                Bsl[lc * 72 + row] = (f16)v;
            }
        }
    __syncthreads();
    {   // write XTn[b][l][o] vectorized
        int row = t >> 1, half = t & 1;
        f16* dst = XTn + ((size_t)b * LL + l0 + row) * HH + half * 32;
        const f16* src = &Bsl[row * 72 + half * 32];
#pragma unroll
        for (int i = 0; i < 4; ++i)
            F4(dst + i * 8) = CF4(src + i * 8);
    }
}

// ---------------------------------------------------------------------------
// Final layer (i=3) + projection, only l = L-1. grid 32 (b), block 128.
// x3 column read is contiguous in XT layout.
// ---------------------------------------------------------------------------
__global__ __launch_bounds__(128) void k_final(const f16* __restrict__ Ofh,
                                               const f16* __restrict__ XT3,
                                               const f16* __restrict__ Ttr,
                                               const float* __restrict__ wsk,
                                               const float* __restrict__ bsk,
                                               const float* __restrict__ wp1,
                                               const float* __restrict__ bp1,
                                               const float* __restrict__ wp2,
                                               const float* __restrict__ bp2,
                                               float* __restrict__ out) {
    __shared__ float tl[128], xl[64], x4[64], y[128];
    const int b = blockIdx.x, t = threadIdx.x;
    tl[t] = (float)Ttr[(size_t)(LL - 1) * 128 + t];
    if (t < 64) xl[t] = (float)XT3[((size_t)b * LL + (LL - 1)) * HH + t];
    __syncthreads();
    if (t < 64) {
        const int o = t;
        float acc = bsk[3 * HH + o];
        const f16* ofp = Ofh + ((size_t)(b * HH + o)) * 128;
        for (int k = 0; k < 128; ++k) acc += (float)ofp[k] * tl[k];
        const float* wp = wsk + (size_t)(3 * HH + o) * HH;
        for (int i = 0; i < 64; ++i) acc += wp[i] * xl[i];
        x4[o] = acc;   // no gelu after last FNO layer
    }
    __syncthreads();
    {
        float acc = bp1[t];
        for (int h = 0; h < 64; ++h) acc += wp1[t * 64 + h] * x4[h];
        y[t] = gelu_tanh(acc);
    }
    __syncthreads();
    if (t < 8) {
        float acc = bp2[t];
        for (int p = 0; p < 128; ++p) acc += wp2[t * 128 + p] * y[p];
        out[b * 8 + t] = acc;   // float32 output
    }
}

// ---------------------------------------------------------------------------
extern "C" void kernel_launch(void* const* d_in, const int* in_sizes, int n_in,
                              void* d_out, int out_size, void* d_ws, size_t ws_size,
                              hipStream_t stream) {
    (void)in_sizes; (void)n_in; (void)out_size; (void)ws_size;
    const float* u   = (const float*)d_in[0];
    const float* z   = (const float*)d_in[1];
    // d_in[2] = t, unused by the reference
    const float* wl  = (const float*)d_in[3];
    const float* bl  = (const float*)d_in[4];
    const float* swr = (const float*)d_in[5];
    const float* swi = (const float*)d_in[6];
    const float* wsk = (const float*)d_in[7];
    const float* bsk = (const float*)d_in[8];
    const float* wp1 = (const float*)d_in[9];
    const float* bp1 = (const float*)d_in[10];
    const float* wp2 = (const float*)d_in[11];
    const float* bp2 = (const float*)d_in[12];
    float* out = (float*)d_out;

    f16* ws    = (f16*)d_ws;
    f16* XTa   = ws;                  // 8,388,608 h (16 MB)  [b][l][h]
    f16* XTb   = XTa + 8388608;       // 8,388,608 h
    f16* Tdt   = XTb + 8388608;       //   524,288 h  [m2][l]
    f16* Ttr   = Tdt + 524288;        //   524,288 h  [l][m2]
    f16* Ofh   = Ttr + 524288;        //   262,144 h  [b][o][m2]
    f16* wskh  = Ofh + 262144;        //    16,384 h
    // total ~36.2 MB.  Y (8 MB fp32 split-K partials) overlays the dead XT buffer.

    k_twiddle<<<1024, 256, 0, stream>>>(Tdt, Ttr, wsk, wskh);
    k_lift<<<dim3(16, 32), 256, 0, stream>>>(u, z, wl, bl, XTa);

    f16* xtc = XTa; f16* xtn = XTb;
    for (int layer = 0; layer < 4; ++layer) {
        float* Y = (float*)xtn;   // dead until recon writes XTn (spec consumes Y first)
        k_dft<<<dim3(8, 32), 256, 0, stream>>>(xtc, Tdt, Y);
        k_spec<<<dim3(16, 32), 256, 0, stream>>>(Y, swr, swi, Ofh, layer);
        if (layer < 3) {
            k_recon<<<dim3(32, 32), 256, 0, stream>>>(Ofh, xtc, Ttr, wskh, bsk,
                                                      xtn, layer);
            f16* tmp = xtc; xtc = xtn; xtn = tmp;
        } else {
            k_final<<<32, 128, 0, stream>>>(Ofh, xtc, Ttr, wsk, bsk,
                                            wp1, bp1, wp2, bp2, out);
        }
    }
}

// Round 5
// 214.203 us; speedup vs baseline: 2.4277x; 1.2317x over previous
//
#include <hip/hip_runtime.h>
#include <math.h>

typedef _Float16 f16;
typedef f16  f16x2 __attribute__((ext_vector_type(2)));
typedef f16  f16x4 __attribute__((ext_vector_type(4)));
typedef f16  f16x8 __attribute__((ext_vector_type(8)));
typedef float f32x4 __attribute__((ext_vector_type(4)));

#define F4(p)  (*(float4*)(p))
#define CF4(p) (*(const float4*)(p))

namespace {
constexpr int LL = 4096;   // sequence
constexpr int HH = 64;     // channels

__device__ __forceinline__ float gelu_fast(float x) {
    // 0.5x(1+tanh(i)) == x*sigmoid(2i); exp-neg form is NaN-free at +/-inf
    float inner = 0.7978845608028654f * (x + 0.044715f * x * x * x);
    float e = __expf(-2.0f * inner);
    return x / (1.0f + e);
}

__device__ __forceinline__ f32x4 mfma16(f16x8 a, f16x8 b, f32x4 c) {
    return __builtin_amdgcn_mfma_f32_16x16x32_f16(a, b, c, 0, 0, 0);
}
} // namespace

// ---------------------------------------------------------------------------
// k_init: fused lift [0,512) + twiddle [512,1536) + wr/wi fp16 cvt [1536,2560)
//   Tdt[m2][l]:  cos(2pi m l/L), -sin                (DFT weights, f16)
//   Ttr[l][m2]: (m==0?1:2cos)/L, (m==0?0:-2sin)/L    (irfft weights, f16)
// Both tables written COALESCED (lane runs along the contiguous dim).
// ---------------------------------------------------------------------------
__global__ __launch_bounds__(256) void k_init(const float* __restrict__ u,
                                              const float* __restrict__ z,
                                              const float* __restrict__ wl,
                                              const float* __restrict__ bl,
                                              const float* __restrict__ wsk,
                                              const float* __restrict__ wr,
                                              const float* __restrict__ wi,
                                              f16* __restrict__ Tdt,
                                              f16* __restrict__ Ttr,
                                              f16* __restrict__ wskh,
                                              f16* __restrict__ wrh,
                                              f16* __restrict__ wih,
                                              f16* __restrict__ XT0) {
    const int bid = blockIdx.x;
    const int t = threadIdx.x;
    if (bid < 512) {
        // ---- lift: XT0[b][l][h], register-tiled 8h x 8l per thread
        const int b = bid >> 4;
        const int l0 = (bid & 15) * 256;
        constexpr int IP = 260;
        __shared__ float in_s[16 * IP];
        __shared__ float wsh[64 * 16];
        __shared__ float bsh[64];
        for (int i = t; i < 1024; i += 256) wsh[i] = wl[i];
        if (t < 64) bsh[t] = bl[t];
#pragma unroll
        for (int q = 0; q < 2; ++q) {
            int f = t + q * 256;
            int l = f >> 1, cq = (f & 1) * 4;
            float4 v = CF4(u + ((size_t)b * LL + l0 + l) * 8 + cq);
            in_s[(cq + 0) * IP + l] = v.x;
            in_s[(cq + 1) * IP + l] = v.y;
            in_s[(cq + 2) * IP + l] = v.z;
            in_s[(cq + 3) * IP + l] = v.w;
        }
        for (int f = t; f < 8 * 256; f += 256) {
            int c = f >> 8, l = f & 255;
            in_s[(8 + c) * IP + l] = z[b * 8 + c];
        }
        __syncthreads();
        const int hg = t >> 5, lsub = t & 31;
        float acc[8][8] = {};
        for (int c = 0; c < 16; ++c) {
            float wv[8], inv[8];
#pragma unroll
            for (int i = 0; i < 8; ++i) wv[i] = wsh[(hg * 8 + i) * 16 + c];
#pragma unroll
            for (int j = 0; j < 8; ++j) inv[j] = in_s[c * IP + lsub + 32 * j];
#pragma unroll
            for (int i = 0; i < 8; ++i)
#pragma unroll
                for (int j = 0; j < 8; ++j) acc[i][j] += wv[i] * inv[j];
        }
#pragma unroll
        for (int j = 0; j < 8; ++j) {
            __attribute__((aligned(16))) f16 hv[8];
#pragma unroll
            for (int i = 0; i < 8; ++i) hv[i] = (f16)(acc[i][j] + bsh[hg * 8 + i]);
            int l = l0 + lsub + 32 * j;
            F4(XT0 + ((size_t)b * LL + l) * HH + hg * 8) = CF4(hv);
        }
    } else if (bid < 1536) {
        // ---- twiddle (both orientations coalesced)
        const int tb = bid - 512;
        const float w0 = 6.283185307179586f / 4096.0f;
        {   // Tdt: lane runs along l
            int m = tb >> 4;
            int l = ((tb & 15) << 8) + t;
            float s, c;
            sincosf((float)((l * m) & 4095) * w0, &s, &c);
            Tdt[(size_t)(2 * m) * LL + l]     = (f16)c;
            Tdt[(size_t)(2 * m + 1) * LL + l] = (f16)(-s);
        }
        {   // Ttr: lane runs along m2 (4B per lane)
            int l = tb * 4 + (t >> 6);
            int m = t & 63;
            float s, c;
            sincosf((float)((l * m) & 4095) * w0, &s, &c);
            const float sc = 1.0f / 4096.0f;
            f16x2 pv;
            pv.x = (f16)((m == 0) ? sc : 2.0f * sc * c);
            pv.y = (f16)((m == 0) ? 0.0f : -2.0f * sc * s);
            *(f16x2*)(Ttr + (size_t)l * 128 + 2 * m) = pv;
        }
        if (tb < 64) {
            int idx = tb * 256 + t;
            wskh[idx] = (f16)wsk[idx];
        }
    } else {
        // ---- wr/wi -> f16 (4 elements each per thread)
        const int cb = bid - 1536;
        size_t base = (size_t)cb * 1024 + t * 4;
        float4 vr = CF4(wr + base);
        float4 vi = CF4(wi + base);
        f16x4 hr, hi;
        hr.x = (f16)vr.x; hr.y = (f16)vr.y; hr.z = (f16)vr.z; hr.w = (f16)vr.w;
        hi.x = (f16)vi.x; hi.y = (f16)vi.y; hi.z = (f16)vi.z; hi.w = (f16)vi.w;
        *(f16x4*)(wrh + base) = hr;
        *(f16x4*)(wih + base) = hi;
    }
}

// ---------------------------------------------------------------------------
// Partial DFT, fp16 MFMA, M=32 split (2 blocks/CU):
//   Y[ch][(b,h)][m2] = sum_{l in 512-chunk} XT[b][l][h] * Tdt[m2][l]   (f16 out)
// grid (16 = ch*2+hhalf, 32 b), block 256 (4 waves). Tile 32 h x 128 m2, K=512.
// ---------------------------------------------------------------------------
__global__ __launch_bounds__(256) void k_dft(const f16* __restrict__ XT,
                                             const f16* __restrict__ Tdt,
                                             f16* __restrict__ Y) {
    __shared__ f16 Asl[32 * 72];    // [h][l-chunk] pitch 72
    __shared__ f16 Bsl[128 * 72];   // [m2][l-chunk] pitch 72
    const int t = threadIdx.x;
    const int ch = blockIdx.x >> 1, h0 = (blockIdx.x & 1) * 32, b = blockIdx.y;
    const int lane = t & 63, wid = t >> 6;
    const int mh = (wid & 1) * 16, n0 = (wid >> 1) * 64;
    const int fm = lane & 15, fq = lane >> 4;
    f32x4 acc[4] = {};
    for (int k0 = 0; k0 < 512; k0 += 64) {
        const int l0 = ch * 512 + k0;
        __syncthreads();
        {   // A: XT[b][l][h0..h0+32] -> Asl[h][l] (LDS transpose, 2-way free)
            int seg = t >> 6;   // 4 segs x 8 h
            f16x8 v = *(const f16x8*)(XT + ((size_t)b * LL + l0 + lane) * HH + h0 + seg * 8);
#pragma unroll
            for (int i = 0; i < 8; ++i) Asl[(seg * 8 + i) * 72 + lane] = v[i];
        }
#pragma unroll
        for (int p = 0; p < 4; ++p) {   // B: Tdt[m2][l0..l0+63]
            int r = (t >> 3) + p * 32;
            F4(&Bsl[r * 72 + (t & 7) * 8]) = CF4(Tdt + (size_t)r * LL + l0 + (t & 7) * 8);
        }
        __syncthreads();
#pragma unroll
        for (int ks = 0; ks < 64; ks += 32) {
            f16x8 a = *(const f16x8*)&Asl[(mh + fm) * 72 + ks + fq * 8];
#pragma unroll
            for (int j = 0; j < 4; ++j) {
                f16x8 bj = *(const f16x8*)&Bsl[(n0 + j * 16 + fm) * 72 + ks + fq * 8];
                acc[j] = mfma16(a, bj, acc[j]);
            }
        }
    }
    f16* yp = Y + ((size_t)ch * 2048 + b * HH + h0) * 128;
#pragma unroll
    for (int j = 0; j < 4; ++j)
#pragma unroll
        for (int r = 0; r < 4; ++r)
            yp[(size_t)(mh + fq * 4 + r) * 128 + n0 + j * 16 + fm] = (f16)acc[j][r];
}

// ---------------------------------------------------------------------------
// Spectral mix + split-K reduce. grid (32 b, 16 og) -> XCD = b%8 (Y/weights
// become XCD-local). f16 Y and weights, fp32 math, f16 out.
// ---------------------------------------------------------------------------
__global__ __launch_bounds__(256) void k_spec(const f16* __restrict__ Y,
                                              const f16* __restrict__ wrh,
                                              const f16* __restrict__ wih,
                                              f16* __restrict__ Ofh, int layer) {
    __shared__ float xsh[64 * 128];
    const int t = threadIdx.x;
    const int b = blockIdx.x;
    const int og = blockIdx.y;
    {   // stage Xf[b] = sum_ch Y[ch][b]  (ascending ch, fp32 accum)
#pragma unroll
        for (int i = 0; i < 4; ++i) {
            int g = t + i * 256;            // f16x8 group, 1024 total
            float s[8] = {};
#pragma unroll
            for (int c = 0; c < 8; ++c) {
                f16x8 v = *(const f16x8*)(Y + ((size_t)c * 2048 + b * HH) * 128 + g * 8);
#pragma unroll
                for (int e = 0; e < 8; ++e) s[e] += (float)v[e];
            }
#pragma unroll
            for (int e = 0; e < 8; ++e) xsh[g * 8 + e] = s[e];
        }
    }
    __syncthreads();
    const int m = t & 63, osub = t >> 6;
    const int o = og * 4 + osub;
    const f16* wrp = wrh + ((size_t)layer * HH + o) * HH * 64 + m;
    const f16* wip = wih + ((size_t)layer * HH + o) * HH * 64 + m;
    float are = 0.0f, aim = 0.0f;
    const float2* xs2 = (const float2*)xsh;
#pragma unroll 8
    for (int i = 0; i < 64; ++i) {
        float2 xv = xs2[i * 64 + m];
        float wrv = (float)wrp[(size_t)i * 64];
        float wiv = (float)wip[(size_t)i * 64];
        are += xv.x * wrv - xv.y * wiv;
        aim += xv.x * wiv + xv.y * wrv;
    }
    f16x2 ov; ov.x = (f16)are; ov.y = (f16)aim;
    *(f16x2*)(Ofh + ((size_t)b * HH + o) * 128 + 2 * m) = ov;
}

// ---------------------------------------------------------------------------
// Recon (layers 0..2), fp16 MFMA, fused K=192 = [Of | Wsk] x [Ttr ; X^T]:
//   x_next[b][o][l] = gelu( sum_k A[o][k]*B[k][l] + bsk[o] )
// Output in transposed layout XTn[b][l][o] (via LDS transpose).
// grid (32 l-tiles of 128, 32 b), block 256 (4 waves), tile 64 o x 128 l.
// ---------------------------------------------------------------------------
__global__ __launch_bounds__(256) void k_recon(const f16* __restrict__ Ofh,
                                               const f16* __restrict__ XT,
                                               const f16* __restrict__ Ttr,
                                               const f16* __restrict__ wskh,
                                               const float* __restrict__ bsk,
                                               f16* __restrict__ XTn,
                                               int layer) {
    __shared__ f16 Asl[64 * 200];   // [o][k 0..191], pitch 200
    __shared__ f16 Bsl[128 * 72];   // [l][k-chunk], pitch 72; reused for transpose
    const int t = threadIdx.x;
    const int l0 = blockIdx.x * 128, b = blockIdx.y;
    const int lane = t & 63, wid = t >> 6;
    const int m0 = (wid & 1) * 32, n0 = (wid >> 1) * 64;
    const int fm = lane & 15, fq = lane >> 4;
    f32x4 acc[2][4] = {};
    {   // stage A = [Of[b] | wskh[layer]]
        int seg = t & 15, row = t >> 4;
#pragma unroll
        for (int p = 0; p < 4; ++p) {
            int r = row + p * 16;
            F4(&Asl[r * 200 + seg * 8]) = CF4(Ofh + ((size_t)(b * HH + r)) * 128 + seg * 8);
        }
        int seg8 = t & 7, row8 = t >> 3;
#pragma unroll
        for (int p = 0; p < 2; ++p) {
            int r = row8 + p * 32;
            F4(&Asl[r * 200 + 128 + seg8 * 8]) =
                CF4(wskh + ((size_t)(layer * HH + r)) * HH + seg8 * 8);
        }
    }
    const int srow = t >> 3, sseg = t & 7;
    for (int k0 = 0; k0 < 192; k0 += 64) {
        __syncthreads();
#pragma unroll
        for (int p = 0; p < 4; ++p) {   // B rows l: Ttr[l][k0..] or XT[b][l][h]
            int r = srow + p * 32;
            const f16* src = (k0 < 128)
                ? (Ttr + (size_t)(l0 + r) * 128 + k0 + sseg * 8)
                : (XT + ((size_t)b * LL + l0 + r) * HH + sseg * 8);
            F4(&Bsl[r * 72 + sseg * 8]) = CF4(src);
        }
        __syncthreads();
#pragma unroll
        for (int ks = 0; ks < 64; ks += 32) {
            f16x8 a0 = *(const f16x8*)&Asl[(m0 + fm) * 200 + k0 + ks + fq * 8];
            f16x8 a1 = *(const f16x8*)&Asl[(m0 + 16 + fm) * 200 + k0 + ks + fq * 8];
#pragma unroll
            for (int j = 0; j < 4; ++j) {
                f16x8 bj = *(const f16x8*)&Bsl[(n0 + j * 16 + fm) * 72 + ks + fq * 8];
                acc[0][j] = mfma16(a0, bj, acc[0][j]);
                acc[1][j] = mfma16(a1, bj, acc[1][j]);
            }
        }
    }
    __syncthreads();   // frag reads done; reuse Bsl as [l][o] staging
#pragma unroll
    for (int i = 0; i < 2; ++i)
#pragma unroll
        for (int r = 0; r < 4; ++r) {
            int row = m0 + i * 16 + fq * 4 + r;
            float bias = bsk[layer * HH + row];
#pragma unroll
            for (int j = 0; j < 4; ++j) {
                float v = gelu_fast(acc[i][j][r] + bias);
                int lc = n0 + j * 16 + fm;
                Bsl[lc * 72 + row] = (f16)v;
            }
        }
    __syncthreads();
    {   // write XTn[b][l][o] vectorized
        int row = t >> 1, half = t & 1;
        f16* dst = XTn + ((size_t)b * LL + l0 + row) * HH + half * 32;
        const f16* src = &Bsl[row * 72 + half * 32];
#pragma unroll
        for (int i = 0; i < 4; ++i)
            F4(dst + i * 8) = CF4(src + i * 8);
    }
}

// ---------------------------------------------------------------------------
// Final layer (i=3) + projection, only l = L-1. grid 32 (b), block 128.
// All operands LDS-staged with +1-padded pitches (conflict-free broadcasts).
// ---------------------------------------------------------------------------
__global__ __launch_bounds__(128) void k_final(const f16* __restrict__ Ofh,
                                               const f16* __restrict__ XT3,
                                               const f16* __restrict__ Ttr,
                                               const float* __restrict__ wsk,
                                               const float* __restrict__ bsk,
                                               const float* __restrict__ wp1,
                                               const float* __restrict__ bp1,
                                               const float* __restrict__ wp2,
                                               const float* __restrict__ bp2,
                                               float* __restrict__ out) {
    __shared__ float ofs[64 * 129];    // Of[b] fp32, pitch 129
    __shared__ float wsks[64 * 65];    // w_skip[3], pitch 65
    __shared__ float wp1s[128 * 65];   // w_p1, pitch 65
    __shared__ float tl[128], xl[64], x4[64], y[128];
    const int b = blockIdx.x, t = threadIdx.x;
    {   // Of[b]: 8192 f16 coalesced
#pragma unroll
        for (int i = 0; i < 8; ++i) {
            int g = t + i * 128;
            f16x8 v = *(const f16x8*)(Ofh + (size_t)b * HH * 128 + g * 8);
            int o = g >> 4, k0 = (g & 15) * 8;
#pragma unroll
            for (int e = 0; e < 8; ++e) ofs[o * 129 + k0 + e] = (float)v[e];
        }
    }
    {   // wsk[3]: 4096 f32
        const float* src = wsk + 3 * HH * HH;
#pragma unroll
        for (int i = 0; i < 8; ++i) {
            int g = t + i * 128;
            float4 v = CF4(src + g * 4);
            int o = g >> 4, c0 = (g & 15) * 4;
            F4(&wsks[o * 65 + c0]) = v;
        }
    }
    {   // wp1: 8192 f32
#pragma unroll
        for (int i = 0; i < 16; ++i) {
            int g = t + i * 128;
            float4 v = CF4(wp1 + g * 4);
            int p = g >> 4, c0 = (g & 15) * 4;
            F4(&wp1s[p * 65 + c0]) = v;
        }
    }
    tl[t] = (float)Ttr[(size_t)(LL - 1) * 128 + t];
    if (t < 64) xl[t] = (float)XT3[((size_t)b * LL + (LL - 1)) * HH + t];
    __syncthreads();
    if (t < 64) {
        const int o = t;
        float acc = bsk[3 * HH + o];
        for (int k = 0; k < 128; ++k) acc += ofs[o * 129 + k] * tl[k];
        for (int i = 0; i < 64; ++i) acc += wsks[o * 65 + i] * xl[i];
        x4[o] = acc;   // no gelu after last FNO layer
    }
    __syncthreads();
    {
        float acc = bp1[t];
        for (int h = 0; h < 64; ++h) acc += wp1s[t * 65 + h] * x4[h];
        y[t] = gelu_fast(acc);
    }
    __syncthreads();
    if (t < 8) {
        float acc = bp2[t];
        for (int p = 0; p < 128; ++p) acc += wp2[t * 128 + p] * y[p];
        out[b * 8 + t] = acc;   // float32 output
    }
}

// ---------------------------------------------------------------------------
extern "C" void kernel_launch(void* const* d_in, const int* in_sizes, int n_in,
                              void* d_out, int out_size, void* d_ws, size_t ws_size,
                              hipStream_t stream) {
    (void)in_sizes; (void)n_in; (void)out_size; (void)ws_size;
    const float* u   = (const float*)d_in[0];
    const float* z   = (const float*)d_in[1];
    // d_in[2] = t, unused by the reference
    const float* wl  = (const float*)d_in[3];
    const float* bl  = (const float*)d_in[4];
    const float* swr = (const float*)d_in[5];
    const float* swi = (const float*)d_in[6];
    const float* wsk = (const float*)d_in[7];
    const float* bsk = (const float*)d_in[8];
    const float* wp1 = (const float*)d_in[9];
    const float* bp1 = (const float*)d_in[10];
    const float* wp2 = (const float*)d_in[11];
    const float* bp2 = (const float*)d_in[12];
    float* out = (float*)d_out;

    f16* ws    = (f16*)d_ws;
    f16* XTa   = ws;                  // 8,388,608 h (16 MB)  [b][l][h]
    f16* XTb   = XTa + 8388608;       // 8,388,608 h
    f16* Tdt   = XTb + 8388608;       //   524,288 h  [m2][l]
    f16* Ttr   = Tdt + 524288;        //   524,288 h  [l][m2]
    f16* Ofh   = Ttr + 524288;        //   262,144 h  [b][o][m2]
    f16* wskh  = Ofh + 262144;        //    16,384 h
    f16* wrh   = wskh + 16384;        // 1,048,576 h
    f16* wih   = wrh + 1048576;       // 1,048,576 h
    // total ~40 MB. Y (4 MB f16 split-K partials) overlays the dead XT buffer.

    k_init<<<2560, 256, 0, stream>>>(u, z, wl, bl, wsk, swr, swi,
                                     Tdt, Ttr, wskh, wrh, wih, XTa);

    f16* xtc = XTa; f16* xtn = XTb;
    for (int layer = 0; layer < 4; ++layer) {
        f16* Y = xtn;   // dead until recon writes XTn (spec consumes Y first)
        k_dft<<<dim3(16, 32), 256, 0, stream>>>(xtc, Tdt, Y);
        k_spec<<<dim3(32, 16), 256, 0, stream>>>(Y, wrh, wih, Ofh, layer);
        if (layer < 3) {
            k_recon<<<dim3(32, 32), 256, 0, stream>>>(Ofh, xtc, Ttr, wskh, bsk,
                                                      xtn, layer);
            f16* tmp = xtc; xtc = xtn; xtn = tmp;
        } else {
            k_final<<<32, 128, 0, stream>>>(Ofh, xtc, Ttr, wsk, bsk,
                                            wp1, bp1, wp2, bp2, out);
        }
    }
}